// Round 14
// baseline (120.779 us; speedup 1.0000x reference)
//
#include <hip/hip_runtime.h>
#include <hip/hip_bf16.h>
#include <math.h>

#define DIM   768
#define BATCH 32
#define SEQ   2048
#define SCALE 0.036084391824351615f  // 1/sqrt(768)

__device__ __forceinline__ float wave_sum(float v) {
#pragma unroll
    for (int o = 32; o > 0; o >>= 1) v += __shfl_xor(v, o, 64);
    return v;
}

__device__ __forceinline__ void fma4(float4& a, float s, const float4& c) {
    a.x += s * c.x; a.y += s * c.y; a.z += s * c.z; a.w += s * c.w;
}
__device__ __forceinline__ float4 add4(const float4& a, const float4& b) {
    return make_float4(a.x + b.x, a.y + b.y, a.z + b.z, a.w + b.w);
}

// ---------------------------------------------------------------------------
// Split-K partial GEMM with dual-source A (concat along K at ksplit):
// part[kc][Mtot][768] = A[M x 64-chunk] @ W[chunk x 768]
// grid = (768/64, Mtot/32, K/64), block = 256.  (R3-proven)
// ---------------------------------------------------------------------------
__global__ __launch_bounds__(256) void gemm_partial(
        const float* __restrict__ A0, int lda0,
        const float* __restrict__ A1, int lda1, int ksplit,
        const float* __restrict__ W,
        float* __restrict__ part, int Mtot,
        const int* __restrict__ step_ptr, int wstride) {
    const float* Wp = W + (step_ptr ? (long)step_ptr[0] * wstride : 0);
    const int jt = blockIdx.x * 64;
    const int r0 = blockIdx.y * 32;
    const int kc = blockIdx.z;
    __shared__ float As[32][33];
    __shared__ float Ws[32][64];
    const int t = threadIdx.x;
    const int j = t & 63;
    const int bg = t >> 6;
    float acc[8];
#pragma unroll
    for (int i = 0; i < 8; i++) acc[i] = 0.f;

    for (int k0 = kc * 64; k0 < kc * 64 + 64; k0 += 32) {
        {   // A tile 32x32
            int r  = t >> 3;
            int kk = (t & 7) * 4;
            int ka = k0 + kk;
            float4 av;
            if (ka < ksplit)
                av = *(const float4*)(A0 + (long)(r0 + r) * lda0 + ka);
            else
                av = *(const float4*)(A1 + (long)(r0 + r) * lda1 + (ka - ksplit));
            As[r][kk] = av.x; As[r][kk + 1] = av.y; As[r][kk + 2] = av.z; As[r][kk + 3] = av.w;
        }
#pragma unroll
        for (int i = 0; i < 2; i++) {  // W tile 32x64, float4 loads
            int idx = t + i * 256;
            int row = idx >> 4, col4 = idx & 15;
            float4 wv = *(const float4*)(Wp + (long)(k0 + row) * DIM + jt + col4 * 4);
            *(float4*)&Ws[row][col4 * 4] = wv;
        }
        __syncthreads();
#pragma unroll 8
        for (int kk = 0; kk < 32; kk++) {
            float wv = Ws[kk][j];
#pragma unroll
            for (int i = 0; i < 8; i++) acc[i] += As[bg * 8 + i][kk] * wv;
        }
        __syncthreads();
    }
#pragma unroll
    for (int i = 0; i < 8; i++)
        part[((long)(kc * Mtot + r0 + bg * 8 + i)) * DIM + jt + j] = acc[i];
}

// ---------------------------------------------------------------------------
// Reduce split-K partials + bias, LayerNorm+ReLU (+optional *wattn fold).
// grid = Mtot, block = 256.  (R3-proven; used for LN1 only)
// ---------------------------------------------------------------------------
__global__ __launch_bounds__(256) void reduce_ln(
        const float* __restrict__ part, int KC, int Mtot,
        const float* __restrict__ bias,
        const int* __restrict__ step_ptr, int bstride,
        const float* __restrict__ g, const float* __restrict__ b,
        const float* __restrict__ wattn,
        float* __restrict__ out) {
    const int row = blockIdx.x;
    const int t = threadIdx.x;
    const float* bp = bias + (step_ptr ? (long)step_ptr[0] * bstride : 0);
    __shared__ float r1[4], r2[4];
    float x[3];
    float s = 0.f, ss = 0.f;
#pragma unroll
    for (int i = 0; i < 3; i++) {
        int jj = t + i * 256;
        float v = bp[jj];
#pragma unroll 4
        for (int kc = 0; kc < KC; kc++)
            v += part[((long)(kc * Mtot + row)) * DIM + jj];
        x[i] = v; s += v; ss += v * v;
    }
    float wsv = wave_sum(s), wss = wave_sum(ss);
    int lane = t & 63, wid = t >> 6;
    if (lane == 0) { r1[wid] = wsv; r2[wid] = wss; }
    __syncthreads();
    s  = r1[0] + r1[1] + r1[2] + r1[3];
    ss = r2[0] + r2[1] + r2[2] + r2[3];
    float mu = s * (1.f / DIM);
    float var = ss * (1.f / DIM) - mu * mu;
    float rs = rsqrtf(var + 1e-5f);
#pragma unroll
    for (int i = 0; i < 3; i++) {
        int jj = t + i * 256;
        float y = (x[i] - mu) * rs * g[jj] + b[jj];
        y = y > 0.f ? y : 0.f;
        if (wattn) y *= wattn[jj];
        out[(long)row * DIM + jj] = y;
    }
}

// Final: reduce + bias, dual LN, ReLU -> next_control. grid = 64, block 256.
__global__ __launch_bounds__(256) void reduce_ln_final(
        const float* __restrict__ part, int KC,
        const float* __restrict__ bias,
        const float* __restrict__ g3, const float* __restrict__ b3,
        const float* __restrict__ g4, const float* __restrict__ b4,
        float* __restrict__ nc) {
    const int row = blockIdx.x;  // 0..63
    const int t = threadIdx.x;
    __shared__ float r1[4], r2[4];
    float x[3];
    float s = 0.f, ss = 0.f;
#pragma unroll
    for (int i = 0; i < 3; i++) {
        int jj = t + i * 256;
        float v = bias[jj];
#pragma unroll 4
        for (int kc = 0; kc < KC; kc++)
            v += part[((long)(kc * 64 + row)) * DIM + jj];
        x[i] = v; s += v; ss += v * v;
    }
    float wsv = wave_sum(s), wss = wave_sum(ss);
    int lane = t & 63, wid = t >> 6;
    if (lane == 0) { r1[wid] = wsv; r2[wid] = wss; }
    __syncthreads();
    s  = r1[0] + r1[1] + r1[2] + r1[3];
    ss = r2[0] + r2[1] + r2[2] + r2[3];
    float mu = s * (1.f / DIM);
    float var = ss * (1.f / DIM) - mu * mu;
    float rs = rsqrtf(var + 1e-5f);
    const float* g  = (row < 32) ? g3 : g4;
    const float* bb = (row < 32) ? b3 : b4;
    int bidx = row & 31;
    int off  = (row < 32) ? 0 : DIM;
#pragma unroll
    for (int i = 0; i < 3; i++) {
        int jj = t + i * 256;
        float y = (x[i] - mu) * rs * g[jj] + bb[jj];
        nc[(long)bidx * (2 * DIM) + off + jj] = y > 0.f ? y : 0.f;
    }
}

// ---------------------------------------------------------------------------
// Fused attention with LN2 folded in (R11/R13-proven structure), with
// BRANCH-SELECTED single accumulate per row: per row exactly one of
// {qm1-only, qm2-only, both} holds (wave-uniform) -> accumulate ev*ctx into
// ONE of accA/accB/accC instead of three chains. Outputs reconstructed:
// mc1 = A+C, mc2 = B+C, ncf = A+B+C (same summands, different add order).
// grid = (SEQ/128, BATCH), 512 threads (8 waves), CHUNK=128.
// ---------------------------------------------------------------------------
__global__ __launch_bounds__(512, 4) void attn_main(
        const float* __restrict__ ctx, const float* __restrict__ part2,
        const float* __restrict__ b_cq,
        const float* __restrict__ ln2_g, const float* __restrict__ ln2_b,
        const float* __restrict__ W_attn, const float* __restrict__ b_attn,
        const float* __restrict__ qm1, const float* __restrict__ qm2,
        float* __restrict__ w, float* __restrict__ zpart,
        float* __restrict__ pvec) {
    const int c = blockIdx.x;   // 0..15
    const int b = blockIdx.y;
    const int t = threadIdx.x;
    const int wave = t >> 6, lane = t & 63;
    __shared__ float4 red[3][192];   // 9216 B
    __shared__ float ush[DIM];       // 3072 B
    __shared__ float sc1[8], sc2[8];

    // ---- LN2 preamble: u[b] from part2 ----
    {
        float ua = b_cq[t];
        float ub = (t < 256) ? b_cq[t + 512] : 0.f;
#pragma unroll 4
        for (int kc = 0; kc < 36; kc++) {
            const float* p2 = part2 + ((long)(kc * 32 + b)) * DIM;
            ua += p2[t];
            if (t < 256) ub += p2[t + 512];
        }
        float v1 = wave_sum(ua + ub);
        float v2 = wave_sum(ua * ua + ub * ub);
        if (lane == 0) { sc1[wave] = v1; sc2[wave] = v2; }
        __syncthreads();
        float s = 0.f, ss = 0.f;
#pragma unroll
        for (int i = 0; i < 8; i++) { s += sc1[i]; ss += sc2[i]; }
        float mu = s * (1.f / DIM);
        float var = ss * (1.f / DIM) - mu * mu;
        float rs = rsqrtf(var + 1e-5f);
        float y = (ua - mu) * rs * ln2_g[t] + ln2_b[t];
        ush[t] = (y > 0.f ? y : 0.f) * W_attn[t];
        if (t < 256) {
            float y2 = (ub - mu) * rs * ln2_g[t + 512] + ln2_b[t + 512];
            ush[t + 512] = (y2 > 0.f ? y2 : 0.f) * W_attn[t + 512];
        }
        __syncthreads();
    }

    const float batt = b_attn[0];
    const long row0 = (long)b * SEQ + c * 128;

    float4 uu[3];
#pragma unroll
    for (int i = 0; i < 3; i++)
        uu[i] = ((const float4*)ush)[lane + i * 64];

    // partitioned accumulators: A = qm1-only rows, B = qm2-only, C = both
    float4 accA[3], accB[3], accC[3];
#pragma unroll
    for (int i = 0; i < 3; i++) {
        accA[i] = make_float4(0.f, 0.f, 0.f, 0.f);
        accB[i] = make_float4(0.f, 0.f, 0.f, 0.f);
        accC[i] = make_float4(0.f, 0.f, 0.f, 0.f);
    }
    float zA = 0.f, zB = 0.f, zC = 0.f;

#pragma unroll 1
    for (int g = 0; g < 4; g++) {
        const int rw = g * 32 + wave * 4;   // 8 waves x 4 rows x 4 groups = 128
        float4 cr[4][3];
        float d[4];
#pragma unroll
        for (int rr = 0; rr < 4; rr++) {
            const float4* crow = (const float4*)(ctx + (row0 + rw + rr) * DIM);
            float dd = 0.f;
#pragma unroll
            for (int i = 0; i < 3; i++) {
                float4 cv = crow[lane + i * 64];
                cr[rr][i] = cv;
                dd += cv.x * uu[i].x + cv.y * uu[i].y + cv.z * uu[i].z + cv.w * uu[i].w;
            }
            d[rr] = wave_sum(dd);
        }
        float lw0 = (d[0] + batt) * SCALE;
        float lw1 = (d[1] + batt) * SCALE;
        float lw2 = (d[2] + batt) * SCALE;
        float lw3 = (d[3] + batt) * SCALE;
        if (lane < 4) {
            float v = lane == 0 ? lw0 : lane == 1 ? lw1 : lane == 2 ? lw2 : lw3;
            w[row0 + rw + lane] = v;
        }
        // masks for the 4 rows: lanes 0-3 qm1, lanes 4-7 qm2
        float mv = 0.f;
        if (lane < 4) mv = qm1[row0 + rw + lane];
        else if (lane < 8) mv = qm2[row0 + rw + lane - 4];
#pragma unroll
        for (int rr = 0; rr < 4; rr++) {
            float a1 = __shfl(mv, rr, 64);
            float a2 = __shfl(mv, rr + 4, 64);
            float lwr = rr == 0 ? lw0 : rr == 1 ? lw1 : rr == 2 ? lw2 : lw3;
            float ev = __expf(lwr);
            // wave-uniform mask combo -> scalar branch, ONE accumulate chain
            unsigned u1 = __builtin_amdgcn_readfirstlane(__float_as_uint(a1));
            unsigned u2 = __builtin_amdgcn_readfirstlane(__float_as_uint(a2));
            if (u1 && u2) {
                zC += ev;
#pragma unroll
                for (int i = 0; i < 3; i++) fma4(accC[i], ev, cr[rr][i]);
            } else if (u1) {
                zA += ev;
#pragma unroll
                for (int i = 0; i < 3; i++) fma4(accA[i], ev, cr[rr][i]);
            } else if (u2) {
                zB += ev;
#pragma unroll
                for (int i = 0; i < 3; i++) fma4(accB[i], ev, cr[rr][i]);
            }
        }
    }
    // reconstruct the 3 outputs: 0=ncf(A+B+C), 1=mc1(A+C), 2=mc2(B+C)
    float zacc[3];
    zacc[0] = zA + zB + zC; zacc[1] = zA + zC; zacc[2] = zB + zC;
    float4 acc[3][3];
#pragma unroll
    for (int i = 0; i < 3; i++) {
        float4 ac = accC[i];
        acc[1][i] = add4(accA[i], ac);
        acc[2][i] = add4(accB[i], ac);
        acc[0][i] = add4(accA[i], add4(accB[i], ac));
    }

    if (lane == 0) {
        float* zp = zpart + ((long)(b * 16 + c) * 8 + wave) * 3;
        zp[0] = zacc[0]; zp[1] = zacc[1]; zp[2] = zacc[2];
    }
    // cross-wave reduce: wave 0 seeds, waves 1-7 add sequentially
    if (wave == 0) {
#pragma unroll
        for (int k = 0; k < 3; k++)
#pragma unroll
            for (int i = 0; i < 3; i++) red[k][lane + i * 64] = acc[k][i];
    }
    __syncthreads();
#pragma unroll 1
    for (int wv = 1; wv < 8; wv++) {
        if (wave == wv) {
#pragma unroll
            for (int k = 0; k < 3; k++)
#pragma unroll
                for (int i = 0; i < 3; i++) {
                    float4 r = red[k][lane + i * 64];
                    r.x += acc[k][i].x; r.y += acc[k][i].y;
                    r.z += acc[k][i].z; r.w += acc[k][i].w;
                    red[k][lane + i * 64] = r;
                }
        }
        __syncthreads();
    }
    for (int idx = t; idx < 576; idx += 512) {
        int k = idx / 192, col = idx - k * 192;
        ((float4*)pvec)[((long)(b * 16 + c) * 3 + k) * 192 + col] = red[k][col];
    }
}

// ---------------------------------------------------------------------------
// Combine chunk partials, l2-normalize -> A6; write attentions output.
// grid = (BATCH, 3): k=0 ncf, k=1 mc1, k=2 mc2. block = 256.
// ---------------------------------------------------------------------------
__global__ __launch_bounds__(256) void combine_norm(
        const float* __restrict__ zpart, const float* __restrict__ pvec,
        const float* __restrict__ w,
        const float* __restrict__ qm1, const float* __restrict__ qm2,
        float* __restrict__ A6, float* __restrict__ attn_out) {
    const int b = blockIdx.x, k = blockIdx.y;
    const int t = threadIdx.x;
    const int lane = t & 63, wid = t >> 6;
    __shared__ float r1[4], r2[4];
    // softmax denominator: 128 contiguous entries per b
    float z = 0.f;
    for (int j = t; j < 128; j += 256)
        z += zpart[((long)b * 128 + j) * 3 + k];
    z = wave_sum(z);
    if (lane == 0) r1[wid] = z;
    __syncthreads();
    z = r1[0] + r1[1] + r1[2] + r1[3];
    // vector combine over 16 chunks
    float v[3] = {0.f, 0.f, 0.f};
    for (int cch = 0; cch < 16; cch++) {
        const float* p = pvec + ((long)(b * 16 + cch) * 3 + k) * DIM;
#pragma unroll
        for (int i = 0; i < 3; i++) v[i] += p[t + i * 256];
    }
    float ss = v[0] * v[0] + v[1] * v[1] + v[2] * v[2];
    float wss = wave_sum(ss);
    if (lane == 0) r2[wid] = wss;
    __syncthreads();
    ss = r2[0] + r2[1] + r2[2] + r2[3];
    float inv = 1.f / fmaxf(sqrtf(ss), 1e-12f);
#pragma unroll
    for (int i = 0; i < 3; i++) {
        int jj = t + i * 256;
        float nv = v[i] * inv;
        if (k == 0) {
            A6[(long)b * (2 * DIM) + DIM + jj] = nv;
            A6[(long)(32 + b) * (2 * DIM) + DIM + jj] = nv;
        } else if (k == 1) {
            A6[(long)b * (2 * DIM) + jj] = nv;
        } else {
            A6[(long)(32 + b) * (2 * DIM) + jj] = nv;
        }
    }
    // attentions output for this (b, k)
    float iz = 1.f / z;
#pragma unroll
    for (int ii = 0; ii < 8; ii++) {
        int s = t + ii * 256;
        float wv = w[(long)b * SEQ + s];
        float m1 = qm1[(long)b * SEQ + s];
        float m2 = qm2[(long)b * SEQ + s];
        bool act = (k == 0) ? (m1 != 0.f || m2 != 0.f) : (k == 1) ? (m1 != 0.f) : (m2 != 0.f);
        attn_out[((long)b * 3 + k) * SEQ + s] = act ? __expf(wv) * iz : 0.f;
    }
}

extern "C" void kernel_launch(void* const* d_in, const int* in_sizes, int n_in,
                              void* d_out, int out_size, void* d_ws, size_t ws_size,
                              hipStream_t stream) {
    const int*   step     = (const int*)  d_in[0];
    const float* ctx      = (const float*)d_in[1];
    const float* question = (const float*)d_in[2];
    const float* control  = (const float*)d_in[3];
    const float* qm1      = (const float*)d_in[4];
    const float* qm2      = (const float*)d_in[5];
    const float* W_pos    = (const float*)d_in[8];
    const float* b_pos    = (const float*)d_in[9];
    const float* ln1_g    = (const float*)d_in[10];
    const float* ln1_b    = (const float*)d_in[11];
    const float* W_cq     = (const float*)d_in[12];
    const float* b_cq     = (const float*)d_in[13];
    const float* ln2_g    = (const float*)d_in[14];
    const float* ln2_b    = (const float*)d_in[15];
    const float* W_attn   = (const float*)d_in[16];
    const float* b_attn   = (const float*)d_in[17];
    const float* W_fuse   = (const float*)d_in[18];
    const float* b_fuse   = (const float*)d_in[19];
    const float* ln3_g    = (const float*)d_in[20];
    const float* ln3_b    = (const float*)d_in[21];
    const float* ln4_g    = (const float*)d_in[22];
    const float* ln4_b    = (const float*)d_in[23];

    float* ws    = (float*)d_ws;
    float* pa    = ws;             // 32*768   = 24576
    float* w     = ws + 49152;     // 32*2048  = 65536
    float* zpart = ws + 114688;    // 32*128*3 = 12288
    float* A6    = ws + 126976;    // 64*1536  = 98304
    float* part2 = ws + 225280;    // 36*32*768 = 884736 (persists through attn)
    float* big   = ws + 1110016;   // gemm1/gemm3 partials, pvec (<=1179648)

    float* nc_out   = (float*)d_out;
    float* attn_out = (float*)d_out + BATCH * 2 * DIM;

    // pa = ln_relu(question @ W_pos[step] + b_pos[step])
    gemm_partial<<<dim3(DIM / 64, 1, DIM / 64), 256, 0, stream>>>(
        question, DIM, question, DIM, 1 << 30, W_pos, big, 32, step, DIM * DIM);
    reduce_ln<<<BATCH, 256, 0, stream>>>(big, DIM / 64, 32, b_pos, step, DIM,
                                         ln1_g, ln1_b, nullptr, pa);

    // part2 = [control | pa] @ W_cq (split-K partials; LN2 folded into attn)
    gemm_partial<<<dim3(DIM / 64, 1, (3 * DIM) / 64), 256, 0, stream>>>(
        control, 2 * DIM, pa, DIM, 2 * DIM, W_cq, part2, 32, nullptr, 0);

    // fused LN2 + single-read attention (512 threads, CHUNK=128)
    attn_main<<<dim3(SEQ / 128, BATCH), 512, 0, stream>>>(
        ctx, part2, b_cq, ln2_g, ln2_b, W_attn, b_attn, qm1, qm2, w, zpart, big);

    // combine + l2norm -> A6; attentions output
    combine_norm<<<dim3(BATCH, 3), 256, 0, stream>>>(
        zpart, big, w, qm1, qm2, A6, attn_out);

    // fused GEMM + dual-LN -> next_control
    gemm_partial<<<dim3(DIM / 64, 2, (2 * DIM) / 64), 256, 0, stream>>>(
        A6, 2 * DIM, A6, 2 * DIM, 1 << 30, W_fuse, big, 64, nullptr, 0);
    reduce_ln_final<<<2 * BATCH, 256, 0, stream>>>(big, (2 * DIM) / 64, b_fuse,
                                                   ln3_g, ln3_b, ln4_g, ln4_b, nc_out);
}

// Round 15
// 94.536 us; speedup vs baseline: 1.2776x; 1.2776x over previous
//
#include <hip/hip_runtime.h>
#include <hip/hip_bf16.h>
#include <math.h>

#define DIM   768
#define BATCH 32
#define SEQ   2048
#define SCALE 0.036084391824351615f  // 1/sqrt(768)

__device__ __forceinline__ float wave_sum(float v) {
#pragma unroll
    for (int o = 32; o > 0; o >>= 1) v += __shfl_xor(v, o, 64);
    return v;
}

__device__ __forceinline__ void fma4(float4& a, float s, const float4& c) {
    a.x += s * c.x; a.y += s * c.y; a.z += s * c.z; a.w += s * c.w;
}

// ---------------------------------------------------------------------------
// Split-K partial GEMM with dual-source A (concat along K at ksplit):
// part[kc][Mtot][768] = A[M x 64-chunk] @ W[chunk x 768]
// grid = (768/64, Mtot/32, K/64), block = 256.  (R3-proven)
// ---------------------------------------------------------------------------
__global__ __launch_bounds__(256) void gemm_partial(
        const float* __restrict__ A0, int lda0,
        const float* __restrict__ A1, int lda1, int ksplit,
        const float* __restrict__ W,
        float* __restrict__ part, int Mtot,
        const int* __restrict__ step_ptr, int wstride) {
    const float* Wp = W + (step_ptr ? (long)step_ptr[0] * wstride : 0);
    const int jt = blockIdx.x * 64;
    const int r0 = blockIdx.y * 32;
    const int kc = blockIdx.z;
    __shared__ float As[32][33];
    __shared__ float Ws[32][64];
    const int t = threadIdx.x;
    const int j = t & 63;
    const int bg = t >> 6;
    float acc[8];
#pragma unroll
    for (int i = 0; i < 8; i++) acc[i] = 0.f;

    for (int k0 = kc * 64; k0 < kc * 64 + 64; k0 += 32) {
        {   // A tile 32x32
            int r  = t >> 3;
            int kk = (t & 7) * 4;
            int ka = k0 + kk;
            float4 av;
            if (ka < ksplit)
                av = *(const float4*)(A0 + (long)(r0 + r) * lda0 + ka);
            else
                av = *(const float4*)(A1 + (long)(r0 + r) * lda1 + (ka - ksplit));
            As[r][kk] = av.x; As[r][kk + 1] = av.y; As[r][kk + 2] = av.z; As[r][kk + 3] = av.w;
        }
#pragma unroll
        for (int i = 0; i < 2; i++) {  // W tile 32x64, float4 loads
            int idx = t + i * 256;
            int row = idx >> 4, col4 = idx & 15;
            float4 wv = *(const float4*)(Wp + (long)(k0 + row) * DIM + jt + col4 * 4);
            *(float4*)&Ws[row][col4 * 4] = wv;
        }
        __syncthreads();
#pragma unroll 8
        for (int kk = 0; kk < 32; kk++) {
            float wv = Ws[kk][j];
#pragma unroll
            for (int i = 0; i < 8; i++) acc[i] += As[bg * 8 + i][kk] * wv;
        }
        __syncthreads();
    }
#pragma unroll
    for (int i = 0; i < 8; i++)
        part[((long)(kc * Mtot + r0 + bg * 8 + i)) * DIM + jt + j] = acc[i];
}

// ---------------------------------------------------------------------------
// Reduce split-K partials + bias, LayerNorm+ReLU (+optional *wattn fold).
// grid = Mtot, block = 256.  (R3-proven; used for LN1 only)
// ---------------------------------------------------------------------------
__global__ __launch_bounds__(256) void reduce_ln(
        const float* __restrict__ part, int KC, int Mtot,
        const float* __restrict__ bias,
        const int* __restrict__ step_ptr, int bstride,
        const float* __restrict__ g, const float* __restrict__ b,
        const float* __restrict__ wattn,
        float* __restrict__ out) {
    const int row = blockIdx.x;
    const int t = threadIdx.x;
    const float* bp = bias + (step_ptr ? (long)step_ptr[0] * bstride : 0);
    __shared__ float r1[4], r2[4];
    float x[3];
    float s = 0.f, ss = 0.f;
#pragma unroll
    for (int i = 0; i < 3; i++) {
        int jj = t + i * 256;
        float v = bp[jj];
#pragma unroll 4
        for (int kc = 0; kc < KC; kc++)
            v += part[((long)(kc * Mtot + row)) * DIM + jj];
        x[i] = v; s += v; ss += v * v;
    }
    float wsv = wave_sum(s), wss = wave_sum(ss);
    int lane = t & 63, wid = t >> 6;
    if (lane == 0) { r1[wid] = wsv; r2[wid] = wss; }
    __syncthreads();
    s  = r1[0] + r1[1] + r1[2] + r1[3];
    ss = r2[0] + r2[1] + r2[2] + r2[3];
    float mu = s * (1.f / DIM);
    float var = ss * (1.f / DIM) - mu * mu;
    float rs = rsqrtf(var + 1e-5f);
#pragma unroll
    for (int i = 0; i < 3; i++) {
        int jj = t + i * 256;
        float y = (x[i] - mu) * rs * g[jj] + b[jj];
        y = y > 0.f ? y : 0.f;
        if (wattn) y *= wattn[jj];
        out[(long)row * DIM + jj] = y;
    }
}

// Final: reduce + bias, dual LN, ReLU -> next_control. grid = 64, block 256.
__global__ __launch_bounds__(256) void reduce_ln_final(
        const float* __restrict__ part, int KC,
        const float* __restrict__ bias,
        const float* __restrict__ g3, const float* __restrict__ b3,
        const float* __restrict__ g4, const float* __restrict__ b4,
        float* __restrict__ nc) {
    const int row = blockIdx.x;  // 0..63
    const int t = threadIdx.x;
    __shared__ float r1[4], r2[4];
    float x[3];
    float s = 0.f, ss = 0.f;
#pragma unroll
    for (int i = 0; i < 3; i++) {
        int jj = t + i * 256;
        float v = bias[jj];
#pragma unroll 4
        for (int kc = 0; kc < KC; kc++)
            v += part[((long)(kc * 64 + row)) * DIM + jj];
        x[i] = v; s += v; ss += v * v;
    }
    float wsv = wave_sum(s), wss = wave_sum(ss);
    int lane = t & 63, wid = t >> 6;
    if (lane == 0) { r1[wid] = wsv; r2[wid] = wss; }
    __syncthreads();
    s  = r1[0] + r1[1] + r1[2] + r1[3];
    ss = r2[0] + r2[1] + r2[2] + r2[3];
    float mu = s * (1.f / DIM);
    float var = ss * (1.f / DIM) - mu * mu;
    float rs = rsqrtf(var + 1e-5f);
    const float* g  = (row < 32) ? g3 : g4;
    const float* bb = (row < 32) ? b3 : b4;
    int bidx = row & 31;
    int off  = (row < 32) ? 0 : DIM;
#pragma unroll
    for (int i = 0; i < 3; i++) {
        int jj = t + i * 256;
        float y = (x[i] - mu) * rs * g[jj] + bb[jj];
        nc[(long)bidx * (2 * DIM) + off + jj] = y > 0.f ? y : 0.f;
    }
}

// ---------------------------------------------------------------------------
// Fused attention with LN2 folded in (R11/R13-proven, best measured config):
// each block reduces part2 -> u[b] in LDS (36 chunks + b_cq -> LN -> ReLU
// -> *W_attn), then the single-ctx-read attention with masked-fma
// accumulation (NO branches in the inner loop — keeps loads pipelined).
// grid = (SEQ/128, BATCH), 512 threads (8 waves), CHUNK=128.
// ---------------------------------------------------------------------------
__global__ __launch_bounds__(512, 4) void attn_main(
        const float* __restrict__ ctx, const float* __restrict__ part2,
        const float* __restrict__ b_cq,
        const float* __restrict__ ln2_g, const float* __restrict__ ln2_b,
        const float* __restrict__ W_attn, const float* __restrict__ b_attn,
        const float* __restrict__ qm1, const float* __restrict__ qm2,
        float* __restrict__ w, float* __restrict__ zpart,
        float* __restrict__ pvec) {
    const int c = blockIdx.x;   // 0..15
    const int b = blockIdx.y;
    const int t = threadIdx.x;
    const int wave = t >> 6, lane = t & 63;
    __shared__ float4 red[3][192];   // 9216 B
    __shared__ float ush[DIM];       // 3072 B
    __shared__ float sc1[8], sc2[8];

    // ---- LN2 preamble: u[b] from part2 ----
    {
        float ua = b_cq[t];
        float ub = (t < 256) ? b_cq[t + 512] : 0.f;
#pragma unroll 4
        for (int kc = 0; kc < 36; kc++) {
            const float* p2 = part2 + ((long)(kc * 32 + b)) * DIM;
            ua += p2[t];
            if (t < 256) ub += p2[t + 512];
        }
        float v1 = wave_sum(ua + ub);
        float v2 = wave_sum(ua * ua + ub * ub);
        if (lane == 0) { sc1[wave] = v1; sc2[wave] = v2; }
        __syncthreads();
        float s = 0.f, ss = 0.f;
#pragma unroll
        for (int i = 0; i < 8; i++) { s += sc1[i]; ss += sc2[i]; }
        float mu = s * (1.f / DIM);
        float var = ss * (1.f / DIM) - mu * mu;
        float rs = rsqrtf(var + 1e-5f);
        float y = (ua - mu) * rs * ln2_g[t] + ln2_b[t];
        ush[t] = (y > 0.f ? y : 0.f) * W_attn[t];
        if (t < 256) {
            float y2 = (ub - mu) * rs * ln2_g[t + 512] + ln2_b[t + 512];
            ush[t + 512] = (y2 > 0.f ? y2 : 0.f) * W_attn[t + 512];
        }
        __syncthreads();
    }

    const float batt = b_attn[0];
    const long row0 = (long)b * SEQ + c * 128;

    float4 uu[3];
#pragma unroll
    for (int i = 0; i < 3; i++)
        uu[i] = ((const float4*)ush)[lane + i * 64];

    float4 acc[3][3];
#pragma unroll
    for (int k = 0; k < 3; k++)
#pragma unroll
        for (int i = 0; i < 3; i++) acc[k][i] = make_float4(0.f, 0.f, 0.f, 0.f);
    float zacc[3] = {0.f, 0.f, 0.f};

#pragma unroll 1
    for (int g = 0; g < 4; g++) {
        const int rw = g * 32 + wave * 4;   // 8 waves x 4 rows x 4 groups = 128
        float4 cr[4][3];
        float d[4];
#pragma unroll
        for (int rr = 0; rr < 4; rr++) {
            const float4* crow = (const float4*)(ctx + (row0 + rw + rr) * DIM);
            float dd = 0.f;
#pragma unroll
            for (int i = 0; i < 3; i++) {
                float4 cv = crow[lane + i * 64];
                cr[rr][i] = cv;
                dd += cv.x * uu[i].x + cv.y * uu[i].y + cv.z * uu[i].z + cv.w * uu[i].w;
            }
            d[rr] = wave_sum(dd);
        }
        float lw0 = (d[0] + batt) * SCALE;
        float lw1 = (d[1] + batt) * SCALE;
        float lw2 = (d[2] + batt) * SCALE;
        float lw3 = (d[3] + batt) * SCALE;
        if (lane < 4) {
            float v = lane == 0 ? lw0 : lane == 1 ? lw1 : lane == 2 ? lw2 : lw3;
            w[row0 + rw + lane] = v;
        }
        // masks for the 4 rows: lanes 0-3 qm1, lanes 4-7 qm2
        float mv = 0.f;
        if (lane < 4) mv = qm1[row0 + rw + lane];
        else if (lane < 8) mv = qm2[row0 + rw + lane - 4];
#pragma unroll
        for (int rr = 0; rr < 4; rr++) {
            float a1 = __shfl(mv, rr, 64);
            float a2 = __shfl(mv, rr + 4, 64);
            float lwr = rr == 0 ? lw0 : rr == 1 ? lw1 : rr == 2 ? lw2 : lw3;
            float ev = __expf(lwr);
            float e0 = (a1 != 0.f || a2 != 0.f) ? ev : 0.f;
            float e1 = (a1 != 0.f) ? ev : 0.f;
            float e2 = (a2 != 0.f) ? ev : 0.f;
            zacc[0] += e0; zacc[1] += e1; zacc[2] += e2;
#pragma unroll
            for (int i = 0; i < 3; i++) {
                fma4(acc[0][i], e0, cr[rr][i]);
                fma4(acc[1][i], e1, cr[rr][i]);
                fma4(acc[2][i], e2, cr[rr][i]);
            }
        }
    }
    if (lane == 0) {
        float* zp = zpart + ((long)(b * 16 + c) * 8 + wave) * 3;
        zp[0] = zacc[0]; zp[1] = zacc[1]; zp[2] = zacc[2];
    }
    // cross-wave reduce: wave 0 seeds, waves 1-7 add sequentially
    if (wave == 0) {
#pragma unroll
        for (int k = 0; k < 3; k++)
#pragma unroll
            for (int i = 0; i < 3; i++) red[k][lane + i * 64] = acc[k][i];
    }
    __syncthreads();
#pragma unroll 1
    for (int wv = 1; wv < 8; wv++) {
        if (wave == wv) {
#pragma unroll
            for (int k = 0; k < 3; k++)
#pragma unroll
                for (int i = 0; i < 3; i++) {
                    float4 r = red[k][lane + i * 64];
                    r.x += acc[k][i].x; r.y += acc[k][i].y;
                    r.z += acc[k][i].z; r.w += acc[k][i].w;
                    red[k][lane + i * 64] = r;
                }
        }
        __syncthreads();
    }
    for (int idx = t; idx < 576; idx += 512) {
        int k = idx / 192, col = idx - k * 192;
        ((float4*)pvec)[((long)(b * 16 + c) * 3 + k) * 192 + col] = red[k][col];
    }
}

// ---------------------------------------------------------------------------
// Combine chunk partials, l2-normalize -> A6; write attentions output.
// grid = (BATCH, 3): k=0 ncf, k=1 mc1, k=2 mc2. block = 256.
// ---------------------------------------------------------------------------
__global__ __launch_bounds__(256) void combine_norm(
        const float* __restrict__ zpart, const float* __restrict__ pvec,
        const float* __restrict__ w,
        const float* __restrict__ qm1, const float* __restrict__ qm2,
        float* __restrict__ A6, float* __restrict__ attn_out) {
    const int b = blockIdx.x, k = blockIdx.y;
    const int t = threadIdx.x;
    const int lane = t & 63, wid = t >> 6;
    __shared__ float r1[4], r2[4];
    // softmax denominator: 128 contiguous entries per b
    float z = 0.f;
    for (int j = t; j < 128; j += 256)
        z += zpart[((long)b * 128 + j) * 3 + k];
    z = wave_sum(z);
    if (lane == 0) r1[wid] = z;
    __syncthreads();
    z = r1[0] + r1[1] + r1[2] + r1[3];
    // vector combine over 16 chunks
    float v[3] = {0.f, 0.f, 0.f};
    for (int cch = 0; cch < 16; cch++) {
        const float* p = pvec + ((long)(b * 16 + cch) * 3 + k) * DIM;
#pragma unroll
        for (int i = 0; i < 3; i++) v[i] += p[t + i * 256];
    }
    float ss = v[0] * v[0] + v[1] * v[1] + v[2] * v[2];
    float wss = wave_sum(ss);
    if (lane == 0) r2[wid] = wss;
    __syncthreads();
    ss = r2[0] + r2[1] + r2[2] + r2[3];
    float inv = 1.f / fmaxf(sqrtf(ss), 1e-12f);
#pragma unroll
    for (int i = 0; i < 3; i++) {
        int jj = t + i * 256;
        float nv = v[i] * inv;
        if (k == 0) {
            A6[(long)b * (2 * DIM) + DIM + jj] = nv;
            A6[(long)(32 + b) * (2 * DIM) + DIM + jj] = nv;
        } else if (k == 1) {
            A6[(long)b * (2 * DIM) + jj] = nv;
        } else {
            A6[(long)(32 + b) * (2 * DIM) + jj] = nv;
        }
    }
    // attentions output for this (b, k)
    float iz = 1.f / z;
#pragma unroll
    for (int ii = 0; ii < 8; ii++) {
        int s = t + ii * 256;
        float wv = w[(long)b * SEQ + s];
        float m1 = qm1[(long)b * SEQ + s];
        float m2 = qm2[(long)b * SEQ + s];
        bool act = (k == 0) ? (m1 != 0.f || m2 != 0.f) : (k == 1) ? (m1 != 0.f) : (m2 != 0.f);
        attn_out[((long)b * 3 + k) * SEQ + s] = act ? __expf(wv) * iz : 0.f;
    }
}

extern "C" void kernel_launch(void* const* d_in, const int* in_sizes, int n_in,
                              void* d_out, int out_size, void* d_ws, size_t ws_size,
                              hipStream_t stream) {
    const int*   step     = (const int*)  d_in[0];
    const float* ctx      = (const float*)d_in[1];
    const float* question = (const float*)d_in[2];
    const float* control  = (const float*)d_in[3];
    const float* qm1      = (const float*)d_in[4];
    const float* qm2      = (const float*)d_in[5];
    const float* W_pos    = (const float*)d_in[8];
    const float* b_pos    = (const float*)d_in[9];
    const float* ln1_g    = (const float*)d_in[10];
    const float* ln1_b    = (const float*)d_in[11];
    const float* W_cq     = (const float*)d_in[12];
    const float* b_cq     = (const float*)d_in[13];
    const float* ln2_g    = (const float*)d_in[14];
    const float* ln2_b    = (const float*)d_in[15];
    const float* W_attn   = (const float*)d_in[16];
    const float* b_attn   = (const float*)d_in[17];
    const float* W_fuse   = (const float*)d_in[18];
    const float* b_fuse   = (const float*)d_in[19];
    const float* ln3_g    = (const float*)d_in[20];
    const float* ln3_b    = (const float*)d_in[21];
    const float* ln4_g    = (const float*)d_in[22];
    const float* ln4_b    = (const float*)d_in[23];

    float* ws    = (float*)d_ws;
    float* pa    = ws;             // 32*768   = 24576
    float* w     = ws + 49152;     // 32*2048  = 65536
    float* zpart = ws + 114688;    // 32*128*3 = 12288
    float* A6    = ws + 126976;    // 64*1536  = 98304
    float* part2 = ws + 225280;    // 36*32*768 = 884736 (persists through attn)
    float* big   = ws + 1110016;   // gemm1/gemm3 partials, pvec (<=1179648)

    float* nc_out   = (float*)d_out;
    float* attn_out = (float*)d_out + BATCH * 2 * DIM;

    // pa = ln_relu(question @ W_pos[step] + b_pos[step])
    gemm_partial<<<dim3(DIM / 64, 1, DIM / 64), 256, 0, stream>>>(
        question, DIM, question, DIM, 1 << 30, W_pos, big, 32, step, DIM * DIM);
    reduce_ln<<<BATCH, 256, 0, stream>>>(big, DIM / 64, 32, b_pos, step, DIM,
                                         ln1_g, ln1_b, nullptr, pa);

    // part2 = [control | pa] @ W_cq (split-K partials; LN2 folded into attn)
    gemm_partial<<<dim3(DIM / 64, 1, (3 * DIM) / 64), 256, 0, stream>>>(
        control, 2 * DIM, pa, DIM, 2 * DIM, W_cq, part2, 32, nullptr, 0);

    // fused LN2 + single-read attention (512 threads, CHUNK=128)
    attn_main<<<dim3(SEQ / 128, BATCH), 512, 0, stream>>>(
        ctx, part2, b_cq, ln2_g, ln2_b, W_attn, b_attn, qm1, qm2, w, zpart, big);

    // combine + l2norm -> A6; attentions output
    combine_norm<<<dim3(BATCH, 3), 256, 0, stream>>>(
        zpart, big, w, qm1, qm2, A6, attn_out);

    // fused GEMM + dual-LN -> next_control
    gemm_partial<<<dim3(DIM / 64, 2, (2 * DIM) / 64), 256, 0, stream>>>(
        A6, 2 * DIM, A6, 2 * DIM, 1 << 30, W_fuse, big, 64, nullptr, 0);
    reduce_ln_final<<<2 * BATCH, 256, 0, stream>>>(big, (2 * DIM) / 64, b_fuse,
                                                   ln3_g, ln3_b, ln4_g, ln4_b, nc_out);
}